// Round 11
// baseline (460.424 us; speedup 1.0000x reference)
//
#include <hip/hip_runtime.h>

typedef _Float16 half8 __attribute__((ext_vector_type(8)));
typedef float floatx4 __attribute__((ext_vector_type(4)));
typedef float float4v __attribute__((ext_vector_type(4)));

__device__ __forceinline__ void gl_lds16f(const float* g, float* l) {
  __builtin_amdgcn_global_load_lds(
      (const __attribute__((address_space(1))) unsigned int*)g,
      (__attribute__((address_space(3))) unsigned int*)l, 16, 0, 0);
}

__device__ __forceinline__ half8 cvt8(float4v u0, float4v u1) {
  half8 h;
  h[0] = (_Float16)u0[0]; h[1] = (_Float16)u0[1];
  h[2] = (_Float16)u0[2]; h[3] = (_Float16)u0[3];
  h[4] = (_Float16)u1[0]; h[5] = (_Float16)u1[1];
  h[6] = (_Float16)u1[2]; h[7] = (_Float16)u1[3];
  return h;
}

// ---------- per-(i, j): NO repack, NO workspace — inline f32->f16 ----------
// r10 lesson: cross-phase handoff through global memory needs a dispatch
// boundary (grid.sync + threadfence delivered stale data across XCD L2s).
// So instead of fusing the repack in, we DELETE it: sim reads raw f32 and
// converts in-registers. Kills the repack kernel, the 78 MB workspace, and
// the harness's per-iteration workspace poison-memsets.
// Fragment mapping identical to the old A''/B'' (epilogue unchanged, RNE
// casts -> bitwise-identical math to the repack path):
//   a-frag: lane l holds A_i[n=tl*16+(l&15), clamp 195][d=s*32+(l>>4)*8..+7]
//   b-frag: lane l holds B_j[m=ct*16+(l&15)][d=s*32+(l>>4)*8..+7]
// A: per-lane f32 global->reg depth-1 prefetch (co-resident blocks share i ->
//    L1/L2-hot, r9-verified FETCH halving kept).
// B: global_load_lds with PER-LANE SCATTERED f32 source (guide m173), LDS
//    lane-linear -> ds_read_b128 conflict-free. Chunk = 2 K-steps (16 KB),
//    dbuf 32 KB. Counted waits only: prologue vmcnt(8); handoff vmcnt(16)
//    (8 a-loads x 2 steps issued after each stage's 4 DMAs). Never vmcnt(0).
__global__ __launch_bounds__(256, 3) void sim_kernel(const float* __restrict__ img,
                                                     const float* __restrict__ txt,
                                                     const int* __restrict__ pm,
                                                     const float* __restrict__ ls,
                                                     float* __restrict__ lpi,
                                                     float* __restrict__ lpt) {
  __shared__ float Bsh[8192];               // [buf2][sc2][ct4][h2][lane*4 f32] = 32 KB

  const int i = blockIdx.x, j = blockIdx.y; // i-fast: co-resident blocks share i
  const int tid = threadIdx.x;
  const int wave = tid >> 6, lane = tid & 63;
  const int r16 = lane & 15;

  // A: per-lane fragment base pointers (f32), dup-pad clamp to row 195
  const float* A1 = img + (size_t)i * 197 * 768 + 768;
  const float* pAf[4];
  {
    const int tls[4] = {wave, wave + 4, wave + 8, 12};
#pragma unroll
    for (int t = 0; t < 4; ++t) {
      int r = tls[t] * 16 + r16;
      if (r > 195) r = 195;
      pAf[t] = A1 + (size_t)r * 768 + (lane >> 4) * 8;
    }
  }
  // B: per-lane scatter base (row m = r16, col-group (lane>>4)*8); stage adds ct/s/h
  const float* Bsrc = txt + (size_t)j * 65 * 768 + 768
                      + (size_t)r16 * 768 + (lane >> 4) * 8;

  // stage chunk cc (K-steps 2cc, 2cc+1): 16 x 1KB pieces, 4 per wave.
  // piece p: sc = p>>3, ct = (p>>1)&3, h = p&1; LDS dest lane-linear.
  auto stage = [&](int cc) {
    const int buf = cc & 1;
#pragma unroll
    for (int k = 0; k < 4; ++k) {
      int p = wave * 4 + k;                 // 0..15
      int sc = p >> 3, ct = (p >> 1) & 3, h = p & 1;
      gl_lds16f(Bsrc + (size_t)(ct * 16) * 768 + (2 * cc + sc) * 32 + h * 4,
                Bsh + buf * 4096 + p * 256);
    }
  };

  // prologue: 4 DMA, then 8 a-loads; converts force the loads to retire, and
  // in-order vmcnt retirement means the (older) DMAs are then provably done.
  stage(0);
  __builtin_amdgcn_sched_barrier(0);
  half8 af[4];
#pragma unroll
  for (int t = 0; t < 4; ++t) {
    float4v u0 = *(const float4v*)(pAf[t]);
    float4v u1 = *(const float4v*)(pAf[t] + 4);
    af[t] = cvt8(u0, u1);
  }
  __builtin_amdgcn_sched_barrier(0);
  asm volatile("s_waitcnt vmcnt(4)" ::: "memory");   // defensive: <=4 left => DMAs done
  __builtin_amdgcn_s_barrier();
  __builtin_amdgcn_sched_barrier(0);

  floatx4 acc[3][4];
  floatx4 acc12 = (floatx4){0.f, 0.f, 0.f, 0.f};
#pragma unroll
  for (int t = 0; t < 3; ++t)
#pragma unroll
    for (int cc = 0; cc < 4; ++cc)
      acc[t][cc] = (floatx4){0.f, 0.f, 0.f, 0.f};

#pragma unroll
  for (int c = 0; c < 12; ++c) {
    if (c > 0) {
      // handoff: 16 a-loads (8 per step x 2) were issued after stage(c)'s
      // last DMA -> vmcnt(16) proves the chunk-c DMAs retired. Counted wait.
      asm volatile("s_waitcnt vmcnt(16)" ::: "memory");
      __builtin_amdgcn_s_barrier();
      __builtin_amdgcn_sched_barrier(0);
    }

#pragma unroll
    for (int sc = 0; sc < 2; ++sc) {
      const int s = c * 2 + sc;

      // b-frags: 2 x ds_read_b128 per ct (lane-linear, conflict-free) + cvt
      const int base = (c & 1) * 4096 + sc * 2048 + lane * 4;
      half8 b[4];
#pragma unroll
      for (int cc = 0; cc < 4; ++cc) {
        int ct = (wave + cc) & 3;           // rotated: [0] is this wave's own group
        float4v f0 = *(const float4v*)(Bsh + base + ct * 512);
        float4v f1 = *(const float4v*)(Bsh + base + ct * 512 + 256);
        b[cc] = cvt8(f0, f1);
      }

      if (sc == 0 && c < 11) {              // next chunk's 4 DMAs fly during compute
        stage(c + 1);
        __builtin_amdgcn_sched_barrier(0);
      }

      __builtin_amdgcn_s_setprio(1);
#pragma unroll
      for (int cc = 0; cc < 4; ++cc) {
        acc[0][cc] = __builtin_amdgcn_mfma_f32_16x16x32_f16(af[0], b[cc], acc[0][cc], 0, 0, 0);
        acc[1][cc] = __builtin_amdgcn_mfma_f32_16x16x32_f16(af[1], b[cc], acc[1][cc], 0, 0, 0);
        acc[2][cc] = __builtin_amdgcn_mfma_f32_16x16x32_f16(af[2], b[cc], acc[2][cc], 0, 0, 0);
      }
      acc12 = __builtin_amdgcn_mfma_f32_16x16x32_f16(af[3], b[0], acc12, 0, 0, 0);
      __builtin_amdgcn_s_setprio(0);

      // depth-1 A-prefetch for step s+1 (8 f32 loads + cvt), after the cluster;
      // L1-hot (shared i) and covered by the other resident blocks.
      if (s < 23) {
#pragma unroll
        for (int t = 0; t < 4; ++t) {
          float4v u0 = *(const float4v*)(pAf[t] + (s + 1) * 32);
          float4v u1 = *(const float4v*)(pAf[t] + (s + 1) * 32 + 4);
          af[t] = cvt8(u0, u1);
        }
      }
      __builtin_amdgcn_sched_barrier(0);
    }
  }

  // ---------------- epilogue (r1-verified, unchanged) ----------------
  const float sgl = ls[0];
  bool msk[4];
  int colc[4];
#pragma unroll
  for (int cc = 0; cc < 4; ++cc) {
    colc[cc] = ((wave + cc) & 3) * 16 + r16;
    msk[cc] = pm[i * 65 + 1 + colc[cc]] != 0;
  }

  float rowsum = 0.f;
  float cmv[4];
#pragma unroll
  for (int t = 0; t < 3; ++t) {
#pragma unroll
    for (int r = 0; r < 4; ++r) {
      float rm = -__builtin_inff();
#pragma unroll
      for (int cc = 0; cc < 4; ++cc) {
        float v = acc[t][cc][r] * sgl;
        rm = fmaxf(rm, msk[cc] ? -__builtin_inff() : v);
      }
#pragma unroll
      for (int off = 1; off < 16; off <<= 1)
        rm = fmaxf(rm, __shfl_xor(rm, off, 64));
      rowsum += rm;
    }
  }
#pragma unroll
  for (int off = 1; off < 64; off <<= 1) rowsum += __shfl_xor(rowsum, off, 64);

  // per-column max over rows 0..191 (unmasked, per reference max_n)
#pragma unroll
  for (int cc = 0; cc < 4; ++cc) {
    float cm = -__builtin_inff();
#pragma unroll
    for (int t = 0; t < 3; ++t)
#pragma unroll
      for (int r = 0; r < 4; ++r)
        cm = fmaxf(cm, acc[t][cc][r] * sgl);
    cm = fmaxf(cm, __shfl_xor(cm, 16, 64));
    cm = fmaxf(cm, __shfl_xor(cm, 32, 64));
    cmv[cc] = cm;
  }

  __syncthreads();                          // all B reads done -> alias Bsh as scratch
  float* colmaxS = Bsh;                     // [4][64]
  float* t12S    = Bsh + 256;               // [4][64]
  float* wsumS   = Bsh + 512;               // [4]

  if (lane == 0) wsumS[wave] = rowsum;
  if (lane < 16) {
#pragma unroll
    for (int cc = 0; cc < 4; ++cc) colmaxS[wave * 64 + colc[cc]] = cmv[cc];
#pragma unroll
    for (int r = 0; r < 4; ++r) t12S[r * 64 + wave * 16 + r16] = acc12[r] * sgl;
  }
  __syncthreads();

  if (tid < 64) {
    const int col = lane;
    bool valid = pm[i * 65 + 1 + col] == 0;
    float t0 = t12S[col], t1 = t12S[64 + col], t2 = t12S[128 + col], t3 = t12S[192 + col];
    float v = fmaxf(fmaxf(colmaxS[col], colmaxS[64 + col]),
                    fmaxf(colmaxS[128 + col], colmaxS[192 + col]));
    v = fmaxf(v, fmaxf(fmaxf(t0, t1), fmaxf(t2, t3)));       // full col max (n=0..195)
    float contrib = valid ? v : 0.f;
    float cntv = valid ? 1.f : 0.f;
    float rs0 = valid ? t0 : -__builtin_inff();
    float rs1 = valid ? t1 : -__builtin_inff();
    float rs2 = valid ? t2 : -__builtin_inff();
    float rs3 = valid ? t3 : -__builtin_inff();
#pragma unroll
    for (int off = 1; off < 64; off <<= 1) {
      contrib += __shfl_xor(contrib, off, 64);
      cntv += __shfl_xor(cntv, off, 64);
      rs0 = fmaxf(rs0, __shfl_xor(rs0, off, 64));
      rs1 = fmaxf(rs1, __shfl_xor(rs1, off, 64));
      rs2 = fmaxf(rs2, __shfl_xor(rs2, off, 64));
      rs3 = fmaxf(rs3, __shfl_xor(rs3, off, 64));
    }
    if (lane == 0) {
      lpt[i * 64 + j] = contrib / cntv;
      float wtot = wsumS[0] + wsumS[1] + wsumS[2] + wsumS[3];
      lpi[i * 64 + j] = (wtot * 0.0625f + rs0 + rs1 + rs2 + rs3) / 196.f;
    }
  }
}

// ---------------- CE losses + targets (2 waves: lpi & lpt in parallel) ------
// out layout: [0] loss | [1..4097) lpi | [4097..8193) lpt | [8193..8257) targets
__global__ __launch_bounds__(128) void ce_kernel(float* __restrict__ out) {
  __shared__ float part[2];
  const int tid = threadIdx.x;
  const int t = tid & 63;
  const float* src = (tid < 64) ? (out + 1) : (out + 1 + 4096);

  float mx = -__builtin_inff();
#pragma unroll
  for (int jj = 0; jj < 64; ++jj) mx = fmaxf(mx, src[t * 64 + jj]);
  float se = 0.f;
#pragma unroll
  for (int jj = 0; jj < 64; ++jj) se += __expf(src[t * 64 + jj] - mx);
  float v = (mx + __logf(se)) - src[t * 64 + t];

#pragma unroll
  for (int off = 1; off < 64; off <<= 1) v += __shfl_xor(v, off, 64);
  if (t == 0) part[tid >> 6] = v;
  __syncthreads();
  if (tid == 0) out[0] = 0.5f * (part[0] + part[1]) / 64.f;
  if (tid < 64) out[1 + 8192 + tid] = (float)tid;   // targets = arange(64)
}

extern "C" void kernel_launch(void* const* d_in, const int* in_sizes, int n_in,
                              void* d_out, int out_size, void* d_ws, size_t ws_size,
                              hipStream_t stream) {
  const float* image = (const float*)d_in[0];   // (64,197,768) f32
  const float* text  = (const float*)d_in[1];   // (64,65,768) f32
  const int*   pm    = (const int*)d_in[2];     // (64,65) i32
  const float* ls    = (const float*)d_in[3];   // scalar
  float* out = (float*)d_out;

  // no workspace, no repack: sim reads raw f32 and converts inline
  dim3 grid(64, 64);   // x = i (fast): resident blocks share A_i (L1/L2-hot)
  sim_kernel<<<grid, 256, 0, stream>>>(image, text, pm, ls, out + 1, out + 1 + 4096);
  ce_kernel<<<1, 128, 0, stream>>>(out);
}